// Round 12
// baseline (535.085 us; speedup 1.0000x reference)
//
#include <hip/hip_runtime.h>
#include <hip/hip_bf16.h>
#include <hip/hip_fp8.h>

#define TT 36
#define FF 18
#define HH 128
#define BB 32
#define BLOCK 512
#define ESP 36    // es row length (bf16 elems), 72 B rows
#define ELP 36    // el row length (floats), 144 B rows

typedef __attribute__((ext_vector_type(4))) float f32x4;
typedef __attribute__((ext_vector_type(4))) unsigned short u16x4;

#define L2E  1.4426950408889634f
#define L2E2 2.8853900817779268f

static __device__ __forceinline__ float bf2f(unsigned short u) {
    unsigned int x = ((unsigned int)u) << 16;
    return __builtin_bit_cast(float, x);
}
static __device__ __forceinline__ unsigned short f2bf(float f) {
    unsigned int x = __builtin_bit_cast(unsigned int, f);
    unsigned int r = (x + 0x7fffu + ((x >> 16) & 1u)) >> 16;
    return (unsigned short)r;
}
#if __has_builtin(__builtin_amdgcn_rcpf)
static __device__ __forceinline__ float frcp(float x) { return __builtin_amdgcn_rcpf(x); }
#else
static __device__ __forceinline__ float frcp(float x) { return 1.f / x; }
#endif
#if __has_builtin(__builtin_amdgcn_exp2f)
static __device__ __forceinline__ float fexp2(float x) { return __builtin_amdgcn_exp2f(x); }
#else
static __device__ __forceinline__ float fexp2(float x) { return __expf(x * 0.69314718056f); }
#endif

// float -> fp8 e4m3 (OCP), RNE
#if __has_builtin(__builtin_amdgcn_cvt_pk_fp8_f32)
static __device__ __forceinline__ unsigned char f2fp8(float f) {
    int v = __builtin_amdgcn_cvt_pk_fp8_f32(f, 0.f, 0, false);
    return (unsigned char)(v & 0xff);
}
#else
static __device__ __forceinline__ unsigned char f2fp8(float f) {
    __hip_fp8_e4m3 q(f);
    return *(unsigned char*)&q;
}
#endif

static __device__ __forceinline__ f32x4 mfma_f8(long a, long b, f32x4 c) {
    return __builtin_amdgcn_mfma_f32_16x16x32_fp8_fp8(a, b, c, 0, 0, 0);
}

union F8x8 { unsigned char b[8]; long l; };

// XOR chunk swizzle for 8-byte fp8 chunks: chunk (c, bb) at slot bb^c of chunk-row c.
static __device__ __forceinline__ unsigned hxoff(int c, int bb) {
    return (unsigned)((c * BB + (bb ^ c)) << 3);
}

__global__ __launch_bounds__(BLOCK, 4) void enc_att_gru(
    const float* __restrict__ seqs, const float* __restrict__ mask,
    const float* __restrict__ Wh,   const float* __restrict__ bh,
    const float* __restrict__ Ws,   const float* __restrict__ bs,
    const float* __restrict__ Wo,   const float* __restrict__ bo,
    const float* __restrict__ W_ih, const float* __restrict__ W_hh,
    const float* __restrict__ b_ih, const float* __restrict__ b_hh,
    float* __restrict__ out)
{
    __shared__ __align__(16) unsigned short es_lds[BB * FF * ESP]; // bf16 Es, 41472 B
    __shared__ float Ws2_lds[TT * TT];                       // [tp][t], pre-scaled L2E2
    __shared__ float bs2_lds[TT];
    __shared__ __align__(16) float wo2_lds[TT];              // -2*wo
    __shared__ __align__(16) float el_lds[BB][ELP];          // El = exp2(L2E2*lin_h), f32
    __shared__ __align__(16) unsigned char h_lds[16 * BB * 8]; // fp8 h, swizzled chunks, 4 KB
    __shared__ __align__(16) unsigned char x_lds[4 * BB * 8];  // fp8 x, swizzled chunks, 1 KB
    __shared__ __align__(16) float mask_t[TT][BB];           // transposed mask, 4.6 KB
    __shared__ __align__(16) long whf_lds[4 * 3 * 64];       // lin_h fp8 B-frags, 6 KB

    const int tid  = threadIdx.x;
    const int wave = tid >> 6;
    const int lane = tid & 63;
    const int l15  = lane & 15;
    const int l4   = lane >> 4;
    const int bbase = blockIdx.x * BB;
    const int bb2a = tid >> 5;       // phase-B row A (0..15)
    const int bb2b = bb2a + 16;      // phase-B row B (16..31)
    const int f2  = tid & 31;        // phase-B feature (valid < 18)
    const int fsafe = (f2 < FF) ? f2 : (FF - 1);

    // ---- stage small tensors ----
    for (int idx = tid; idx < TT * TT; idx += BLOCK) {
        int t = idx / TT, tp = idx - t * TT;
        Ws2_lds[tp * TT + t] = L2E2 * Ws[idx];      // transposed + scaled
    }
    if (tid < TT) { bs2_lds[tid] = L2E2 * bs[tid]; wo2_lds[tid] = -2.f * Wo[tid]; }
    for (int idx = tid; idx < BB * TT; idx += BLOCK) {
        int bb = idx / TT, t = idx - bb * TT;
        mask_t[t][bb] = mask[(size_t)(bbase + bb) * TT + t];
    }
    for (int idx = tid; idx < 16 * BB * 2; idx += BLOCK) ((int*)h_lds)[idx] = 0;
    for (int idx = tid; idx < 4 * BB * 2; idx += BLOCK) ((int*)x_lds)[idx] = 0;
    // lin_h fp8 B-frag table: (kt, wgrp, l) -> Wh[wgrp*16 + (l&15)][kt*32 + ((l>>4)&3)*8 + jj]
    for (int e = tid; e < 4 * 3 * 64; e += BLOCK) {
        int kt = e / 192;
        int w  = (e / 64) % 3;
        int l  = e & 63;
        int tcolw = w * 16 + (l & 15);
        int kb = kt * 32 + ((l >> 4) & 3) * 8;
        F8x8 u;
#pragma unroll
        for (int jj = 0; jj < 8; ++jj)
            u.b[jj] = (tcolw < TT) ? f2fp8(Wh[(size_t)tcolw * HH + kb + jj]) : (unsigned char)0;
        whf_lds[e] = u.l;
    }
    __syncthreads();

    // ---- precompute Es[bb][f][t] = exp2( L2E2*(bs[t] + sum_tp seq[bb][tp][f]*Ws[t][tp]) ) as bf16 ----
    for (int task = tid; task < BB * FF; task += BLOCK) {
        const int bb = task / FF;
        const int f  = task - bb * FF;
        const size_t sb = (size_t)(bbase + bb) * (TT * FF) + f;
        unsigned short* srow = &es_lds[task * ESP];
        for (int c = 0; c < 3; ++c) {              // t in chunks of 12
            float acc[12];
#pragma unroll
            for (int j = 0; j < 12; ++j) acc[j] = bs2_lds[c * 12 + j];
            for (int tp = 0; tp < TT; ++tp) {
                float s = seqs[sb + (size_t)tp * FF];
#pragma unroll
                for (int j = 0; j < 12; ++j)
                    acc[j] = fmaf(s, Ws2_lds[tp * TT + c * 12 + j], acc[j]);
            }
#pragma unroll
            for (int j = 0; j < 12; ++j) srow[c * 12 + j] = f2bf(fexp2(acc[j]));
        }
    }

    // ---- persistent fp8 weight fragments (self-consistent k-map: k = kt*32 + l4*8 + j) ----
    long whh[3][4];
    for (int g = 0; g < 3; ++g)
        for (int kt = 0; kt < 4; ++kt) {
            const int o = g * HH + 16 * wave + l15;
            F8x8 u;
#pragma unroll
            for (int jj = 0; jj < 8; ++jj) {
                int k = kt * 32 + l4 * 8 + jj;
                u.b[jj] = f2fp8(W_hh[(size_t)o * HH + k]);
            }
            whh[g][kt] = u.l;
        }
    long wih[3];
    for (int g = 0; g < 3; ++g) {
        const int o = g * HH + 16 * wave + l15;
        F8x8 u;
#pragma unroll
        for (int jj = 0; jj < 8; ++jj) {
            int f = l4 * 8 + jj;
            u.b[jj] = (f < FF) ? f2fp8(W_ih[(size_t)o * FF + f]) : (unsigned char)0;
        }
        wih[g] = u.l;
    }
    // lin_h duty: waves 0-2 -> row-tile 0, waves 4-6 -> row-tile 1
    const int wgrp = (wave < 4) ? wave : (wave - 4);
    const bool linh_wave = (wgrp < 3);
    const int lrt  = (wave < 4) ? 0 : 1;
    const int tcol = wgrp * 16 + l15;
    const int junit = 16 * wave + l15;   // GRU unit this lane owns (same for both row-tiles)
    const float brz_r = b_ih[junit] + b_hh[junit];
    const float brz_z = b_ih[HH + junit] + b_hh[HH + junit];
    const float bn_i  = b_ih[2 * HH + junit];
    const float bn_h  = b_hh[2 * HH + junit];
    const float bh_reg = (linh_wave && tcol < TT) ? bh[tcol] : 0.f;
    float c0 = bo[0];
    for (int tp = 0; tp < TT; ++tp) c0 += Wo[tp];   // e = c0 + sum wo2[t]*rcp(1+Es*El)

    float seq_curA = seqs[(size_t)(bbase + bb2a) * (TT * FF) + fsafe];
    float seq_curB = seqs[(size_t)(bbase + bb2b) * (TT * FF) + fsafe];

    float h_prev[2][4]  = {{0.f,0.f,0.f,0.f},{0.f,0.f,0.f,0.f}};
    float out_acc[2][4] = {{0.f,0.f,0.f,0.f},{0.f,0.f,0.f,0.f}};

    __syncthreads();

    for (int t = 0; t < TT; ++t) {
        // ---- Phase A: lin_h MFMA -> El (6 waves; waves 3,7 pass) ----
        if (linh_wave) {
            long ha0[4];
#pragma unroll
            for (int kt = 0; kt < 4; ++kt)
                ha0[kt] = *(const long*)(h_lds + hxoff(kt * 4 + l4, lrt * 16 + l15));
            f32x4 a = {0.f, 0.f, 0.f, 0.f};
#pragma unroll
            for (int kt = 0; kt < 4; ++kt)
                a = mfma_f8(ha0[kt], whf_lds[kt * 192 + wgrp * 64 + lane], a);
            if (tcol < TT) {
#pragma unroll
                for (int r = 0; r < 4; ++r)
                    el_lds[lrt * 16 + l4 * 4 + r][tcol] = fexp2((a[r] + bh_reg) * L2E2);
            }
        }
        __syncthreads();   // el visible

        // ---- Phase B: e-scores for 2 rows/lane (bf16 Es, interleaved chains) + softmax + x ----
        {
            const unsigned short* srA = &es_lds[(bb2a * FF + fsafe) * ESP];
            const unsigned short* srB = &es_lds[(bb2b * FF + fsafe) * ESP];
            const float* lrA = &el_lds[bb2a][0];
            const float* lrB = &el_lds[bb2b][0];
            float a0 = c0, a1 = 0.f, a2 = 0.f, a3 = 0.f;
            float b0 = c0, b1 = 0.f, b2 = 0.f, b3 = 0.f;
#pragma unroll
            for (int g = 0; g < 9; ++g) {
                u16x4 ua = *(const u16x4*)(srA + g * 4);
                u16x4 ub = *(const u16x4*)(srB + g * 4);
                f32x4 la = *(const f32x4*)(lrA + g * 4);
                f32x4 lb = *(const f32x4*)(lrB + g * 4);
                f32x4 wv = *(const f32x4*)(&wo2_lds[g * 4]);
                a0 = fmaf(wv[0], frcp(fmaf(bf2f(ua[0]), la[0], 1.f)), a0);
                a1 = fmaf(wv[1], frcp(fmaf(bf2f(ua[1]), la[1], 1.f)), a1);
                a2 = fmaf(wv[2], frcp(fmaf(bf2f(ua[2]), la[2], 1.f)), a2);
                a3 = fmaf(wv[3], frcp(fmaf(bf2f(ua[3]), la[3], 1.f)), a3);
                b0 = fmaf(wv[0], frcp(fmaf(bf2f(ub[0]), lb[0], 1.f)), b0);
                b1 = fmaf(wv[1], frcp(fmaf(bf2f(ub[1]), lb[1], 1.f)), b1);
                b2 = fmaf(wv[2], frcp(fmaf(bf2f(ub[2]), lb[2], 1.f)), b2);
                b3 = fmaf(wv[3], frcp(fmaf(bf2f(ub[3]), lb[3], 1.f)), b3);
            }
            float eA = (a0 + a1) + (a2 + a3);
            float eB = (b0 + b1) + (b2 + b3);
            // |e| <= |bo| + sum|wo| ~ 1.5 -> exp2 can't overflow; skip max pass
            float pA = (f2 < FF) ? fexp2(L2E * eA) : 0.f;
            float pB = (f2 < FF) ? fexp2(L2E * eB) : 0.f;
            float sA = pA, sB = pB;
#pragma unroll
            for (int d = 1; d <= 16; d <<= 1) {
                sA += __shfl_xor(sA, d);
                sB += __shfl_xor(sB, d);
            }
            if (f2 < FF) {
                x_lds[hxoff(f2 >> 3, bb2a) + (f2 & 7)] = f2fp8(pA * frcp(sA) * seq_curA);
                x_lds[hxoff(f2 >> 3, bb2b) + (f2 & 7)] = f2fp8(pB * frcp(sB) * seq_curB);
                if (t + 1 < TT) {
                    seq_curA = seqs[(size_t)(bbase + bb2a) * (TT * FF) + (size_t)(t + 1) * FF + f2];
                    seq_curB = seqs[(size_t)(bbase + bb2b) * (TT * FF) + (size_t)(t + 1) * FF + f2];
                }
            }
        }
        __syncthreads();   // x visible

        // ---- Phase C: per row-tile, gh+gi MFMAs + GRU elementwise + h store ----
#pragma unroll
        for (int rt = 0; rt < 2; ++rt) {
            long ha[4];
#pragma unroll
            for (int kt = 0; kt < 4; ++kt)
                ha[kt] = *(const long*)(h_lds + hxoff(kt * 4 + l4, rt * 16 + l15));
            f32x4 ar = {0.f,0.f,0.f,0.f}, az = {0.f,0.f,0.f,0.f}, an = {0.f,0.f,0.f,0.f};
#pragma unroll
            for (int kt = 0; kt < 4; ++kt) {
                ar = mfma_f8(ha[kt], whh[0][kt], ar);
                az = mfma_f8(ha[kt], whh[1][kt], az);
                an = mfma_f8(ha[kt], whh[2][kt], an);
            }
            long xa = *(const long*)(x_lds + hxoff(l4, rt * 16 + l15));
            ar = mfma_f8(xa, wih[0], ar);
            az = mfma_f8(xa, wih[1], az);
            f32x4 zero4 = {0.f, 0.f, 0.f, 0.f};
            f32x4 agi = mfma_f8(xa, wih[2], zero4);
            f32x4 mv = *(const f32x4*)(&mask_t[t][rt * 16 + l4 * 4]);
#pragma unroll
            for (int r = 0; r < 4; ++r) {
                int bb = rt * 16 + l4 * 4 + r;
                float rg = frcp(1.f + fexp2(-L2E * (ar[r] + brz_r)));
                float zg = frcp(1.f + fexp2(-L2E * (az[r] + brz_z)));
                float gin = agi[r] + bn_i + rg * (an[r] + bn_h);
                float ng = fmaf(-2.f, frcp(1.f + fexp2(L2E2 * gin)), 1.f);
                float hn = fmaf(zg, h_prev[rt][r] - ng, ng);
                h_prev[rt][r] = hn;
                out_acc[rt][r] = fmaf(hn, mv[r], out_acc[rt][r]);
                h_lds[hxoff(junit >> 3, bb) + (junit & 7)] = f2fp8(hn);
            }
        }
        __syncthreads();   // h ready for next step
    }

#pragma unroll
    for (int rt = 0; rt < 2; ++rt)
#pragma unroll
        for (int r = 0; r < 4; ++r) {
            int bb = rt * 16 + l4 * 4 + r;
            out[(size_t)(bbase + bb) * HH + junit] = out_acc[rt][r];
        }
}

extern "C" void kernel_launch(void* const* d_in, const int* in_sizes, int n_in,
                              void* d_out, int out_size, void* d_ws, size_t ws_size,
                              hipStream_t stream) {
    const float* seqs = (const float*)d_in[0];
    const float* mask = (const float*)d_in[1];
    const float* Wh   = (const float*)d_in[2];
    const float* bh   = (const float*)d_in[3];
    const float* Ws   = (const float*)d_in[4];
    const float* bs   = (const float*)d_in[5];
    const float* Wo   = (const float*)d_in[6];
    const float* bo   = (const float*)d_in[7];
    const float* W_ih = (const float*)d_in[8];
    const float* W_hh = (const float*)d_in[9];
    const float* b_ih = (const float*)d_in[10];
    const float* b_hh = (const float*)d_in[11];
    float* out = (float*)d_out;

    const int Btot = in_sizes[0] / (TT * FF);   // 16384
    const int grid = Btot / BB;                 // 512
    enc_att_gru<<<grid, BLOCK, 0, stream>>>(seqs, mask, Wh, bh, Ws, bs, Wo, bo,
                                            W_ih, W_hh, b_ih, b_hh, out);
}

// Round 13
// 241.804 us; speedup vs baseline: 2.2129x; 2.2129x over previous
//
#include <hip/hip_runtime.h>
#include <hip/hip_bf16.h>
#include <hip/hip_fp8.h>

#define TT 36
#define FF 18
#define HH 128
#define BB 16
#define BLOCK 512
#define ESP 36    // es row length (bf16 elems), 72 B rows
#define ELP 36    // el row length (floats), 144 B rows

typedef __attribute__((ext_vector_type(4))) float f32x4;
typedef __attribute__((ext_vector_type(4))) unsigned short u16x4;

#define L2E  1.4426950408889634f
#define L2E2 2.8853900817779268f

static __device__ __forceinline__ float bf2f(unsigned short u) {
    unsigned int x = ((unsigned int)u) << 16;
    return __builtin_bit_cast(float, x);
}
static __device__ __forceinline__ unsigned short f2bf(float f) {
    unsigned int x = __builtin_bit_cast(unsigned int, f);
    unsigned int r = (x + 0x7fffu + ((x >> 16) & 1u)) >> 16;
    return (unsigned short)r;
}
#if __has_builtin(__builtin_amdgcn_rcpf)
static __device__ __forceinline__ float frcp(float x) { return __builtin_amdgcn_rcpf(x); }
#else
static __device__ __forceinline__ float frcp(float x) { return 1.f / x; }
#endif
#if __has_builtin(__builtin_amdgcn_exp2f)
static __device__ __forceinline__ float fexp2(float x) { return __builtin_amdgcn_exp2f(x); }
#else
static __device__ __forceinline__ float fexp2(float x) { return __expf(x * 0.69314718056f); }
#endif

// float -> fp8 e4m3 (OCP), RNE
#if __has_builtin(__builtin_amdgcn_cvt_pk_fp8_f32)
static __device__ __forceinline__ unsigned char f2fp8(float f) {
    int v = __builtin_amdgcn_cvt_pk_fp8_f32(f, 0.f, 0, false);
    return (unsigned char)(v & 0xff);
}
#else
static __device__ __forceinline__ unsigned char f2fp8(float f) {
    __hip_fp8_e4m3 q(f);
    return *(unsigned char*)&q;
}
#endif

static __device__ __forceinline__ f32x4 mfma_f8(long a, long b, f32x4 c) {
    return __builtin_amdgcn_mfma_f32_16x16x32_fp8_fp8(a, b, c, 0, 0, 0);
}

union F8x8 { unsigned char b[8]; long l; };

// XOR chunk swizzle for 8-byte fp8 chunks: chunk (c, bb) at slot bb^c of chunk-row c.
static __device__ __forceinline__ unsigned hxoff(int c, int bb) {
    return (unsigned)((c * BB + (bb ^ c)) << 3);
}

__global__ __launch_bounds__(BLOCK, 4) void enc_att_gru(
    const float* __restrict__ seqs, const float* __restrict__ mask,
    const float* __restrict__ Wh,   const float* __restrict__ bh,
    const float* __restrict__ Ws,   const float* __restrict__ bs,
    const float* __restrict__ Wo,   const float* __restrict__ bo,
    const float* __restrict__ W_ih, const float* __restrict__ W_hh,
    const float* __restrict__ b_ih, const float* __restrict__ b_hh,
    float* __restrict__ out)
{
    __shared__ __align__(16) unsigned short es_lds[BB * FF * ESP]; // bf16 Es, 20736 B
    __shared__ float Ws2_lds[TT * TT];                       // [tp][t], pre-scaled L2E2
    __shared__ float bs2_lds[TT];
    __shared__ __align__(16) float wo2_lds[TT];              // -2*wo
    __shared__ __align__(16) float el_lds[BB][ELP];          // El = exp2(L2E2*lin_h), f32
    __shared__ __align__(16) unsigned char h_lds[16 * BB * 8]; // fp8 h, swizzled chunks
    __shared__ __align__(16) unsigned char x_lds[4 * BB * 8];  // fp8 x, swizzled chunks
    __shared__ __align__(16) float mask_t[TT][BB];           // transposed mask
    __shared__ __align__(16) long whf_lds[4 * 3 * 64];       // lin_h fp8 B-frags, 6 KB
    __shared__ __align__(16) long wih_lds[3 * BLOCK];        // gi fp8 B-frags per-lane, 12 KB

    const int tid  = threadIdx.x;
    const int wave = tid >> 6;
    const int lane = tid & 63;
    const int l15  = lane & 15;
    const int l4   = lane >> 4;
    const int bbase = blockIdx.x * BB;
    const int bb2 = tid >> 5;      // phase-B batch row (0..15)
    const int f2  = tid & 31;      // phase-B feature (valid < 18)
    const int fsafe = (f2 < FF) ? f2 : (FF - 1);

    // ---- stage small tensors ----
    for (int idx = tid; idx < TT * TT; idx += BLOCK) {
        int t = idx / TT, tp = idx - t * TT;
        Ws2_lds[tp * TT + t] = L2E2 * Ws[idx];      // transposed + scaled
    }
    if (tid < TT) { bs2_lds[tid] = L2E2 * bs[tid]; wo2_lds[tid] = -2.f * Wo[tid]; }
    for (int idx = tid; idx < BB * TT; idx += BLOCK) {
        int bb = idx / TT, t = idx - bb * TT;
        mask_t[t][bb] = mask[(size_t)(bbase + bb) * TT + t];
    }
    for (int idx = tid; idx < 16 * BB * 2; idx += BLOCK) ((int*)h_lds)[idx] = 0;
    for (int idx = tid; idx < 4 * BB * 2; idx += BLOCK) ((int*)x_lds)[idx] = 0;
    // lin_h fp8 B-frag table: (kt, w, l) -> Wh[w*16 + (l&15)][kt*32 + ((l>>4)&3)*8 + jj]
    for (int e = tid; e < 4 * 3 * 64; e += BLOCK) {
        int kt = e / 192;
        int w  = (e / 64) % 3;
        int l  = e & 63;
        int tcolw = w * 16 + (l & 15);
        int kb = kt * 32 + ((l >> 4) & 3) * 8;
        F8x8 u;
#pragma unroll
        for (int jj = 0; jj < 8; ++jj)
            u.b[jj] = (tcolw < TT) ? f2fp8(Wh[(size_t)tcolw * HH + kb + jj]) : (unsigned char)0;
        whf_lds[e] = u.l;
    }
    // gi fp8 B-frag per-lane table: (g, l) -> W_ih[g*HH + 16*(l>>6) + (l&15)][((l>>4)&3)*8 + jj]
    for (int e = tid; e < 3 * BLOCK; e += BLOCK) {
        int g = e >> 9;
        int l = e & (BLOCK - 1);
        const int o = g * HH + 16 * (l >> 6) + (l & 15);
        F8x8 u;
#pragma unroll
        for (int jj = 0; jj < 8; ++jj) {
            int f = ((l >> 4) & 3) * 8 + jj;
            u.b[jj] = (f < FF) ? f2fp8(W_ih[(size_t)o * FF + f]) : (unsigned char)0;
        }
        wih_lds[e] = u.l;
    }
    __syncthreads();

    // ---- precompute Es[bb][f][t] = exp2( L2E2*(bs[t] + sum_tp seq[bb][tp][f]*Ws[t][tp]) ) as bf16 ----
    if (f2 < FF) {
        const size_t sb = (size_t)(bbase + bb2) * (TT * FF) + f2;
        unsigned short* srow = &es_lds[(bb2 * FF + f2) * ESP];
        for (int c = 0; c < 3; ++c) {              // t in chunks of 12
            float acc[12];
#pragma unroll
            for (int j = 0; j < 12; ++j) acc[j] = bs2_lds[c * 12 + j];
            for (int tp = 0; tp < TT; ++tp) {
                float s = seqs[sb + (size_t)tp * FF];
#pragma unroll
                for (int j = 0; j < 12; ++j)
                    acc[j] = fmaf(s, Ws2_lds[tp * TT + c * 12 + j], acc[j]);
            }
#pragma unroll
            for (int j = 0; j < 12; ++j) srow[c * 12 + j] = f2bf(fexp2(acc[j]));
        }
    }

    // ---- persistent fp8 whh fragments (self-consistent k-map: k = kt*32 + l4*8 + j) ----
    long whh[3][4];
    for (int g = 0; g < 3; ++g)
        for (int kt = 0; kt < 4; ++kt) {
            const int o = g * HH + 16 * wave + l15;
            F8x8 u;
#pragma unroll
            for (int jj = 0; jj < 8; ++jj) {
                int k = kt * 32 + l4 * 8 + jj;
                u.b[jj] = f2fp8(W_hh[(size_t)o * HH + k]);
            }
            whh[g][kt] = u.l;
        }
    const int tcol = 16 * wave + l15;
    const int junit = 16 * wave + l15;
    const float brz_r = b_ih[junit] + b_hh[junit];
    const float brz_z = b_ih[HH + junit] + b_hh[HH + junit];
    const float bn_i  = b_ih[2 * HH + junit];
    const float bn_h  = b_hh[2 * HH + junit];
    const float bh_reg = (wave < 3 && tcol < TT) ? bh[tcol] : 0.f;
    float c0 = bo[0];
    for (int tp = 0; tp < TT; ++tp) c0 += Wo[tp];   // e = c0 + sum wo2[t]*rcp(1+Es*El)

    float seq_cur = seqs[(size_t)(bbase + bb2) * (TT * FF) + fsafe];

    float h_prev[4]  = {0.f, 0.f, 0.f, 0.f};
    float out_acc[4] = {0.f, 0.f, 0.f, 0.f};

    __syncthreads();

    for (int t = 0; t < TT; ++t) {
        // ---- Phase A: h A-frags + lin_h (fp8 MFMA) -> El + gh MFMAs ----
        long ha[4];
#pragma unroll
        for (int kt = 0; kt < 4; ++kt)
            ha[kt] = *(const long*)(h_lds + hxoff(kt * 4 + l4, l15));
        if (wave < 3) {
            f32x4 a = {0.f, 0.f, 0.f, 0.f};
#pragma unroll
            for (int kt = 0; kt < 4; ++kt)
                a = mfma_f8(ha[kt], whf_lds[kt * 192 + wave * 64 + lane], a);
            if (tcol < TT) {
#pragma unroll
                for (int r = 0; r < 4; ++r)
                    el_lds[l4 * 4 + r][tcol] = fexp2((a[r] + bh_reg) * L2E2);
            }
        }
        f32x4 acc_r = {0.f,0.f,0.f,0.f}, acc_z = {0.f,0.f,0.f,0.f}, acc_n = {0.f,0.f,0.f,0.f};
#pragma unroll
        for (int kt = 0; kt < 4; ++kt) {
            acc_r = mfma_f8(ha[kt], whh[0][kt], acc_r);
            acc_z = mfma_f8(ha[kt], whh[1][kt], acc_z);
            acc_n = mfma_f8(ha[kt], whh[2][kt], acc_n);
        }
        __syncthreads();   // el visible

        // ---- Phase B: e-scores (bf16 Es, limited unroll) + no-max softmax + x ----
        {
            const unsigned short* srow = &es_lds[(bb2 * FF + fsafe) * ESP];
            const float* lrow = &el_lds[bb2][0];
            float a0 = c0, a1 = 0.f, a2 = 0.f, a3 = 0.f;
#pragma unroll 3
            for (int g = 0; g < 9; ++g) {
                u16x4 sv = *(const u16x4*)(srow + g * 4);
                f32x4 lv = *(const f32x4*)(lrow + g * 4);
                f32x4 wv = *(const f32x4*)(&wo2_lds[g * 4]);
                a0 = fmaf(wv[0], frcp(fmaf(bf2f(sv[0]), lv[0], 1.f)), a0);
                a1 = fmaf(wv[1], frcp(fmaf(bf2f(sv[1]), lv[1], 1.f)), a1);
                a2 = fmaf(wv[2], frcp(fmaf(bf2f(sv[2]), lv[2], 1.f)), a2);
                a3 = fmaf(wv[3], frcp(fmaf(bf2f(sv[3]), lv[3], 1.f)), a3);
            }
            float eacc = (a0 + a1) + (a2 + a3);
            // |e| <= |bo| + sum|wo| ~ 1.5 -> exp2 can't overflow; skip max pass
            float p = (f2 < FF) ? fexp2(L2E * eacc) : 0.f;
            float s = p;
#pragma unroll
            for (int d = 1; d <= 16; d <<= 1) s += __shfl_xor(s, d);
            if (f2 < FF) {
                x_lds[hxoff(f2 >> 3, bb2) + (f2 & 7)] = f2fp8(p * frcp(s) * seq_cur);
                if (t + 1 < TT)
                    seq_cur = seqs[(size_t)(bbase + bb2) * (TT * FF) + (size_t)(t + 1) * FF + f2];
            }
        }
        __syncthreads();   // x visible

        // ---- Phase C: gi MFMA (wih from LDS) + GRU elementwise + h store ----
        long xa = *(const long*)(x_lds + hxoff(l4, l15));
        long w0 = wih_lds[tid];
        long w1 = wih_lds[BLOCK + tid];
        long w2 = wih_lds[2 * BLOCK + tid];
        acc_r = mfma_f8(xa, w0, acc_r);
        acc_z = mfma_f8(xa, w1, acc_z);
        f32x4 zero4 = {0.f, 0.f, 0.f, 0.f};
        f32x4 acc_gi = mfma_f8(xa, w2, zero4);
        f32x4 mv = *(const f32x4*)(&mask_t[t][l4 * 4]);
#pragma unroll
        for (int r = 0; r < 4; ++r) {
            int bb = l4 * 4 + r;
            float rg = frcp(1.f + fexp2(-L2E * (acc_r[r] + brz_r)));
            float zg = frcp(1.f + fexp2(-L2E * (acc_z[r] + brz_z)));
            float gin = acc_gi[r] + bn_i + rg * (acc_n[r] + bn_h);
            float ng = fmaf(-2.f, frcp(1.f + fexp2(L2E2 * gin)), 1.f);
            float hn = fmaf(zg, h_prev[r] - ng, ng);
            h_prev[r] = hn;
            out_acc[r] = fmaf(hn, mv[r], out_acc[r]);
            h_lds[hxoff(junit >> 3, bb) + (junit & 7)] = f2fp8(hn);
        }
        __syncthreads();   // h ready for next step
    }

#pragma unroll
    for (int r = 0; r < 4; ++r) {
        int bb = l4 * 4 + r;
        out[(size_t)(bbase + bb) * HH + junit] = out_acc[r];
    }
}

extern "C" void kernel_launch(void* const* d_in, const int* in_sizes, int n_in,
                              void* d_out, int out_size, void* d_ws, size_t ws_size,
                              hipStream_t stream) {
    const float* seqs = (const float*)d_in[0];
    const float* mask = (const float*)d_in[1];
    const float* Wh   = (const float*)d_in[2];
    const float* bh   = (const float*)d_in[3];
    const float* Ws   = (const float*)d_in[4];
    const float* bs   = (const float*)d_in[5];
    const float* Wo   = (const float*)d_in[6];
    const float* bo   = (const float*)d_in[7];
    const float* W_ih = (const float*)d_in[8];
    const float* W_hh = (const float*)d_in[9];
    const float* b_ih = (const float*)d_in[10];
    const float* b_hh = (const float*)d_in[11];
    float* out = (float*)d_out;

    const int Btot = in_sizes[0] / (TT * FF);   // 16384
    const int grid = Btot / BB;                 // 1024
    enc_att_gru<<<grid, BLOCK, 0, stream>>>(seqs, mask, Wh, bh, Ws, bs, Wo, bo,
                                            W_ih, W_hh, b_ih, b_hh, out);
}